// Round 7
// baseline (4996.670 us; speedup 1.0000x reference)
//
#include <hip/hip_runtime.h>
#include <math.h>

constexpr int SEQ_L = 2048;
constexpr int EDIM  = 300;
constexpr int NCLS  = 20;
constexpr unsigned SENT = 0xFFA5A5A5u;  // NaN payload: unproducible by finite math

typedef float f32x4 __attribute__((ext_vector_type(4)));

// ---------------------------------------------------------------------------
// init: Hbuf[0] = h_0 = zeros; Hbuf[1..2048] = sentinel. (ws poisoned 0xAA.)
// Hbuf is (SEQ_L+1) x [2 dir][512] f32 = 2049*1024 dwords = 524544 uint4.
// ---------------------------------------------------------------------------
__global__ __launch_bounds__(256) void init_kernel(uint4* H) {
  const int NT = 513 * 256;
  int idx = blockIdx.x * blockDim.x + threadIdx.x;
  const uint4 z = {0u, 0u, 0u, 0u};
  const uint4 s = {SENT, SENT, SENT, SENT};
#pragma unroll
  for (int i = 0; i < 4; ++i) {
    int q = i * NT + idx;
    if (q < 524544) H[q] = (q < 256) ? z : s;
  }
}

// ---------------------------------------------------------------------------
// gi = x @ Wih^T + bih (+ bhh folded for r,z). grid (SEQ_L/8, 2), block 256.
// ---------------------------------------------------------------------------
__global__ __launch_bounds__(256) void gi_kernel(
    const int* __restrict__ seq, const float* __restrict__ emb,
    const float* __restrict__ Wih_f, const float* __restrict__ bih_f,
    const float* __restrict__ bhh_f,
    const float* __restrict__ Wih_b, const float* __restrict__ bih_b,
    const float* __restrict__ bhh_b,
    float* __restrict__ gi_f, float* __restrict__ gi_b) {
  const int d = blockIdx.y;
  const float* Wih = d ? Wih_b : Wih_f;
  const float* bih = d ? bih_b : bih_f;
  const float* bhh = d ? bhh_b : bhh_f;
  float* gi = d ? gi_b : gi_f;
  const int t0 = blockIdx.x * 8;
  const int tid = threadIdx.x;

  __shared__ float xs[8][304];

  for (int i = tid; i < 8 * 75; i += 256) {
    int tt = i / 75, u = i - tt * 75;
    int t = t0 + tt;
    int s = seq[d ? (SEQ_L - 1 - t) : t];
    const float4* p = reinterpret_cast<const float4*>(emb + (size_t)s * EDIM);
    float4 v = p[u];
    xs[tt][u * 4 + 0] = v.x; xs[tt][u * 4 + 1] = v.y;
    xs[tt][u * 4 + 2] = v.z; xs[tt][u * 4 + 3] = v.w;
  }
  __syncthreads();

  for (int rr = 0; rr < 6; ++rr) {
    int j = rr * 256 + tid;
    const float4* wrow = reinterpret_cast<const float4*>(Wih + (size_t)j * EDIM);
    float acc[8];
#pragma unroll
    for (int tt = 0; tt < 8; ++tt) acc[tt] = 0.0f;
    for (int q = 0; q < EDIM / 4; ++q) {
      float4 w = wrow[q];
#pragma unroll
      for (int tt = 0; tt < 8; ++tt)
        acc[tt] += w.x * xs[tt][4 * q] + w.y * xs[tt][4 * q + 1] +
                   w.z * xs[tt][4 * q + 2] + w.w * xs[tt][4 * q + 3];
    }
    float bb = bih[j] + (j < 1024 ? bhh[j] : 0.0f);
#pragma unroll
    for (int tt = 0; tt < 8; ++tt)
      gi[(size_t)(t0 + tt) * 1536 + j] = acc[tt] + bb;
  }
}

// ---------------------------------------------------------------------------
// Recurrence: 32 WGs x 512 thr (8 waves). WG (dir, b) owns j0=b*32..+31.
// Wave w owns 4 outputs jw=j0+w*4..+3 (rows r,z,n for those j: 12 rows,
// 8 cols/lane). Per step: wave polls its 64-dword slice of the write-once
// sentinel history, deposits to LDS (parity double-buffered -> ONE
// syncthreads/step), dots, intra-wave transpose-reduce, per-wave gate math
// via shuffles, immediate 16B store. No sync2, no wave-0 serialization.
// ---------------------------------------------------------------------------
__global__ __launch_bounds__(512, 2) void rnn_kernel(
    const float* __restrict__ Whh_f, const float* __restrict__ bhh_f,
    const float* __restrict__ Whh_b, const float* __restrict__ bhh_b,
    const float* __restrict__ gi_f, const float* __restrict__ gi_b,
    float* Hbuf) {  // [SEQ_L+1][2 dir][512]
  const int tid  = threadIdx.x;
  const int lane = tid & 63;
  const int w    = tid >> 6;           // wave 0..7
  const int blk  = blockIdx.x;         // 0..31
  const int dir  = blk >> 4;
  const int j0   = (blk & 15) * 32;    // WG's 32 h-outputs
  const int jw   = j0 + w * 4;         // this wave's 4 h-outputs

  const float* Whh = dir ? Whh_b : Whh_f;
  const float* bhh = dir ? bhh_b : bhh_f;
  const float* gi  = dir ? gi_b : gi_f;

  alignas(16) __shared__ float hsh[2][512];   // parity double-buffer
  alignas(16) __shared__ float part[8][12][68];

  // wave w, row r = g*4+jj -> Whh row g*512 + jw + jj; lane cols lane*8..+7
  f32x4 Wv[24];
#pragma unroll
  for (int g = 0; g < 3; ++g)
#pragma unroll
    for (int jj = 0; jj < 4; ++jj) {
      const f32x4* rp = reinterpret_cast<const f32x4*>(
                            Whh + (size_t)(g * 512 + jw + jj) * 512) +
                        lane * 2;
      Wv[(g * 4 + jj) * 2]     = rp[0];
      Wv[(g * 4 + jj) * 2 + 1] = rp[1];
    }

  const int jj = lane & 3;
  float bhn = 0.0f;
  if (lane < 4) bhn = bhh[1024 + jw + lane];
  float hprev = 0.0f;  // lanes 0-3: h_t[jw+lane], carried in-register

  const int pollOff = dir * 512 + w * 64 + lane;

  for (int t = 0; t < SEQ_L; ++t) {
    const int p = t & 1;

    // gi for this wave's 4 j's, laid out like the rowsums (lane<12):
    // lane L: gate g=L>>2, col jw+(L&3)
    float giv = 0.0f;
    if (lane < 12)
      giv = gi[(size_t)t * 1536 + (lane >> 2) * 512 + jw + jj];

    // poll own 64-float slice of h_t (each dword is its own validity flag)
    const float* hp = Hbuf + (size_t)t * 1024 + pollOff;
    float hvp;
    for (;;) {
      hvp = __hip_atomic_load(hp, __ATOMIC_RELAXED, __HIP_MEMORY_SCOPE_AGENT);
      if (__ballot(__float_as_uint(hvp) == SENT) == 0ull) break;
    }
    hsh[p][w * 64 + lane] = hvp;
    __syncthreads();  // the ONLY barrier per step (parity buffer kills WAR)

    const f32x4* hq = reinterpret_cast<const f32x4*>(&hsh[p][lane * 8]);
    f32x4 h0 = hq[0], h1 = hq[1];

    float s_[12];
#pragma unroll
    for (int r = 0; r < 12; ++r) {
      f32x4 w0 = Wv[2 * r], w1 = Wv[2 * r + 1];
      s_[r] = w0.x * h0.x + w0.y * h0.y + w0.z * h0.z + w0.w * h0.w +
              w1.x * h1.x + w1.y * h1.y + w1.z * h1.z + w1.w * h1.w;
    }

    // intra-wave LDS transpose-reduce (proven pattern)
#pragma unroll
    for (int r = 0; r < 12; ++r) part[w][r][lane] = s_[r];
    __builtin_amdgcn_wave_barrier();
    float sv = 0.0f;
    {
      int r = lane < 12 ? lane : 0;
      const f32x4* rowp = reinterpret_cast<const f32x4*>(&part[w][r][0]);
      f32x4 a4 = rowp[0];
#pragma unroll
      for (int q = 1; q < 16; ++q) a4 += rowp[q];
      sv = (a4.x + a4.y) + (a4.z + a4.w);
    }

    // gather z/n gate terms to lanes 0-3 (shuffles executed by all lanes)
    float s_z = __shfl(sv, 4 + jj, 64);
    float g_z = __shfl(giv, 4 + jj, 64);
    float s_n = __shfl(sv, 8 + jj, 64);
    float g_n = __shfl(giv, 8 + jj, 64);

    if (lane < 4) {
      float rr = 1.0f / (1.0f + __expf(-(giv + sv)));     // r-gate (own lane)
      float zz = 1.0f / (1.0f + __expf(-(g_z + s_z)));    // z-gate
      float nn = tanhf(g_n + rr * (s_n + bhn));           // n-gate
      float hnew = (1.0f - zz) * nn + zz * hprev;
      hprev = hnew;
      __hip_atomic_store(Hbuf + (size_t)(t + 1) * 1024 + dir * 512 + jw + lane,
                         hnew, __ATOMIC_RELAXED, __HIP_MEMORY_SCOPE_AGENT);
    }
  }
}

// ---------------------------------------------------------------------------
// classifier: hid = relu(W1 @ [hf;hb] + b1); logits = W2 @ hid + b2; softmax
// ---------------------------------------------------------------------------
__global__ __launch_bounds__(1024) void cls_kernel(
    const float* __restrict__ Hfin,  // Hbuf slot SEQ_L: [dir][512]
    const float* __restrict__ W1, const float* __restrict__ b1,
    const float* __restrict__ W2, const float* __restrict__ b2,
    float* __restrict__ out) {
  __shared__ float hcat[1024];
  __shared__ float hid[512];
  __shared__ float logits[NCLS];
  const int tid = threadIdx.x;
  hcat[tid] = Hfin[tid];
  __syncthreads();

  const int lane = tid & 63, widx = tid >> 6;
  for (int rr = 0; rr < 32; ++rr) {
    int row = widx * 32 + rr;
    const float4* wrow = reinterpret_cast<const float4*>(W1 + (size_t)row * 1024);
    float acc = 0.0f;
#pragma unroll
    for (int c = 0; c < 4; ++c) {
      int k = c * 256 + lane * 4;
      float4 v = wrow[c * 64 + lane];
      acc += v.x * hcat[k] + v.y * hcat[k + 1] + v.z * hcat[k + 2] +
             v.w * hcat[k + 3];
    }
#pragma unroll
    for (int mask = 32; mask >= 1; mask >>= 1) acc += __shfl_xor(acc, mask, 64);
    if (lane == 0) hid[row] = fmaxf(acc + b1[row], 0.0f);
  }
  __syncthreads();

  if (tid < NCLS) {
    const float4* wrow = reinterpret_cast<const float4*>(W2 + (size_t)tid * 512);
    float acc = 0.0f;
    for (int q = 0; q < 128; ++q) {
      float4 v = wrow[q];
      int k = q * 4;
      acc += v.x * hid[k] + v.y * hid[k + 1] + v.z * hid[k + 2] +
             v.w * hid[k + 3];
    }
    logits[tid] = acc + b2[tid];
  }
  __syncthreads();

  if (tid == 0) {
    float m = -1e30f;
    for (int i = 0; i < NCLS; ++i) m = fmaxf(m, logits[i]);
    float s = 0.0f;
    float e[NCLS];
    for (int i = 0; i < NCLS; ++i) { e[i] = __expf(logits[i] - m); s += e[i]; }
    float inv = 1.0f / s;
    for (int i = 0; i < NCLS; ++i) out[i] = e[i] * inv;
  }
}

// ---------------------------------------------------------------------------
extern "C" void kernel_launch(void* const* d_in, const int* in_sizes, int n_in,
                              void* d_out, int out_size, void* d_ws,
                              size_t ws_size, hipStream_t stream) {
  (void)in_sizes; (void)n_in; (void)out_size; (void)ws_size;
  const int*   seq   = (const int*)d_in[0];
  const float* emb   = (const float*)d_in[1];
  const float* Wih_f = (const float*)d_in[2];
  const float* Whh_f = (const float*)d_in[3];
  const float* bih_f = (const float*)d_in[4];
  const float* bhh_f = (const float*)d_in[5];
  const float* Wih_b = (const float*)d_in[6];
  const float* Whh_b = (const float*)d_in[7];
  const float* bih_b = (const float*)d_in[8];
  const float* bhh_b = (const float*)d_in[9];
  const float* W1    = (const float*)d_in[10];
  const float* b1    = (const float*)d_in[11];
  const float* W2    = (const float*)d_in[12];
  const float* b2    = (const float*)d_in[13];
  float* out = (float*)d_out;

  float* gi_f = (float*)d_ws;                   // 2048*1536 f32 (12.6 MB)
  float* gi_b = gi_f + (size_t)SEQ_L * 1536;    // 12.6 MB
  float* Hbuf = gi_b + (size_t)SEQ_L * 1536;    // 2049*1024 f32 (8.4 MB)

  hipLaunchKernelGGL(init_kernel, dim3(513), dim3(256), 0, stream,
                     (uint4*)Hbuf);
  hipLaunchKernelGGL(gi_kernel, dim3(SEQ_L / 8, 2), dim3(256), 0, stream,
                     seq, emb, Wih_f, bih_f, bhh_f, Wih_b, bih_b, bhh_b,
                     gi_f, gi_b);
  hipLaunchKernelGGL(rnn_kernel, dim3(32), dim3(512), 0, stream,
                     Whh_f, bhh_f, Whh_b, bhh_b, gi_f, gi_b, Hbuf);
  hipLaunchKernelGGL(cls_kernel, dim3(1), dim3(1024), 0, stream,
                     Hbuf + (size_t)SEQ_L * 1024, W1, b1, W2, b2, out);
}